// Round 1
// baseline (977.935 us; speedup 1.0000x reference)
//
#include <hip/hip_runtime.h>
#include <hip/hip_bf16.h>
#include <hip/hip_fp16.h>

typedef _Float16 f16;
typedef _Float16 f16x4 __attribute__((ext_vector_type(4)));
typedef _Float16 f16x8 __attribute__((ext_vector_type(8)));
typedef float f32x4 __attribute__((ext_vector_type(4)));

#define NB 8192
#define ND 1024
#define NU 1024
#define NE 16
#define BM 32

// ---------------- prep: transpose-cast W [E][D][U] f32 -> WT [E][U][D] f16 ----------------
__global__ __launch_bounds__(256) void k_transpose_cast(const float* __restrict__ W,
                                                        f16* __restrict__ WT) {
  __shared__ f16 tile[64][68];  // +4 pad
  const int e = blockIdx.z;
  const int u0 = blockIdx.x * 64;
  const int d0 = blockIdx.y * 64;
  const int t = threadIdx.x;
  const int r = t >> 4;          // 0..15
  const int c = (t & 15) << 2;   // 0..60
  const float* src = W + (size_t)e * ND * NU;
  f16* dst = WT + (size_t)e * NU * ND;
#pragma unroll
  for (int i = 0; i < 4; ++i) {
    const int rr = r + i * 16;
    const float4 v = *(const float4*)(src + (size_t)(d0 + rr) * NU + (u0 + c));
    tile[rr][c + 0] = (f16)v.x;
    tile[rr][c + 1] = (f16)v.y;
    tile[rr][c + 2] = (f16)v.z;
    tile[rr][c + 3] = (f16)v.w;
  }
  __syncthreads();
#pragma unroll
  for (int i = 0; i < 4; ++i) {
    const int rr = r + i * 16;
    f16x4 h;
    h[0] = tile[c + 0][rr];
    h[1] = tile[c + 1][rr];
    h[2] = tile[c + 2][rr];
    h[3] = tile[c + 3][rr];
    *(f16x4*)(dst + (size_t)(u0 + rr) * ND + (d0 + c)) = h;
  }
}

// ---------------- main: fused GEMM + softmax + entity-weighted combine ----------------
// 256 blocks x 512 threads. Block owns 32 rows of B. 8 waves, wave w owns cols [w*128, w*128+128).
// Per e: logits tile in regs (acc[2][8] f32x4), softmax over U, out_acc += tp*prob.
#define LOADB(buf, kk)                                                      \
  {                                                                         \
    _Pragma("unroll") for (int n_ = 0; n_ < 8; ++n_) buf[n_] =              \
        *(const f16x8*)(wt_e + (size_t)(n_ * 16) * ND + (kk));              \
  }

__global__ __launch_bounds__(512, 2) void k_proj(const float* __restrict__ X,
                                                 const float* __restrict__ TP,
                                                 const f16* __restrict__ WT,
                                                 const float* __restrict__ BIAS,
                                                 float* __restrict__ OUT) {
  // LDS: A_s [32][1032] f16 (pad 8 elems; row stride 2064 B) = 66048 B
  //      tp_s [32][16] f32 = 2048 B ; redm [32][8] = 1024 B ; reds [32][8] = 1024 B
  __shared__ alignas(16) unsigned char lds[66048 + 2048 + 1024 + 1024];
  unsigned char* A_s = lds;
  float* tp_s = (float*)(lds + 66048);
  float* redm = (float*)(lds + 66048 + 2048);
  float* reds = (float*)(lds + 66048 + 2048 + 1024);

  const int t = threadIdx.x;
  const int w = t >> 6;    // wave 0..7
  const int l = t & 63;    // lane
  const int g = l >> 4;    // k-group 0..3
  const int ln = l & 15;   // 0..15
  const int b0 = blockIdx.x * BM;

  // ---- stage A panel (32 x 1024) fp32 -> fp16 in LDS, once ----
#pragma unroll
  for (int i = 0; i < 16; ++i) {
    const int idx = (i * 512 + t) << 2;   // element index, 4 at a time
    const int row = idx >> 10;
    const int col = idx & 1023;
    const float4 v = *(const float4*)(X + (size_t)(b0 + row) * ND + col);
    f16x4 h;
    h[0] = (f16)v.x; h[1] = (f16)v.y; h[2] = (f16)v.z; h[3] = (f16)v.w;
    *(f16x4*)(A_s + row * 2064 + (col << 1)) = h;
  }
  // tp staging: 32*16 = 512 values
  tp_s[t] = TP[(size_t)(b0 + (t >> 4)) * NE + (t & 15)];
  __syncthreads();

  f32x4 out_acc[2][8];
#pragma unroll
  for (int m = 0; m < 2; ++m)
#pragma unroll
    for (int n = 0; n < 8; ++n) out_acc[m][n] = (f32x4){0.f, 0.f, 0.f, 0.f};

  // per-lane base into WT for B fragments: row u = w*128 + n*16 + ln, k offset g*8
  const f16* wt_e = WT + (size_t)(w * 128 + ln) * ND + g * 8;

  f16x8 fa[8], fb[8];
  LOADB(fa, 0);

  for (int e = 0; e < NE; ++e) {
    f32x4 acc[2][8];
#pragma unroll
    for (int m = 0; m < 2; ++m)
#pragma unroll
      for (int n = 0; n < 8; ++n) acc[m][n] = (f32x4){0.f, 0.f, 0.f, 0.f};

#pragma unroll 1
    for (int kk = 0; kk < 1024; kk += 64) {
      // prefetch second half-step
      LOADB(fb, kk + 32);
      {
        const f16x8 a0 = *(const f16x8*)(A_s + ln * 2064 + ((kk + g * 8) << 1));
        const f16x8 a1 = *(const f16x8*)(A_s + (16 + ln) * 2064 + ((kk + g * 8) << 1));
#pragma unroll
        for (int n = 0; n < 8; ++n) {
          acc[0][n] = __builtin_amdgcn_mfma_f32_16x16x32_f16(a0, fa[n], acc[0][n], 0, 0, 0);
          acc[1][n] = __builtin_amdgcn_mfma_f32_16x16x32_f16(a1, fa[n], acc[1][n], 0, 0, 0);
        }
      }
      if (kk + 64 < 1024) {
        LOADB(fa, kk + 64);
      } else if (e + 1 < NE) {
        wt_e += (size_t)NU * ND;      // advance to next entity
        LOADB(fa, 0);                 // cross-entity prefetch (hidden under epilogue)
      }
      {
        const f16x8 a0 = *(const f16x8*)(A_s + ln * 2064 + ((kk + 32 + g * 8) << 1));
        const f16x8 a1 = *(const f16x8*)(A_s + (16 + ln) * 2064 + ((kk + 32 + g * 8) << 1));
#pragma unroll
        for (int n = 0; n < 8; ++n) {
          acc[0][n] = __builtin_amdgcn_mfma_f32_16x16x32_f16(a0, fb[n], acc[0][n], 0, 0, 0);
          acc[1][n] = __builtin_amdgcn_mfma_f32_16x16x32_f16(a1, fb[n], acc[1][n], 0, 0, 0);
        }
      }
    }

    // ---- epilogue: bias + softmax over U + weighted accumulate ----
    const float* bp = BIAS + (size_t)e * NU + w * 128 + ln;
    float bv[8];
#pragma unroll
    for (int n = 0; n < 8; ++n) bv[n] = bp[n * 16];
#pragma unroll
    for (int m = 0; m < 2; ++m)
#pragma unroll
      for (int n = 0; n < 8; ++n)
#pragma unroll
        for (int r = 0; r < 4; ++r) acc[m][n][r] += bv[n];

    // row max: local over 8 nblks, then 16-lane group shuffle, then cross-wave via LDS
    float rm[2][4];
#pragma unroll
    for (int m = 0; m < 2; ++m)
#pragma unroll
      for (int r = 0; r < 4; ++r) {
        float v = acc[m][0][r];
#pragma unroll
        for (int n = 1; n < 8; ++n) v = fmaxf(v, acc[m][n][r]);
        v = fmaxf(v, __shfl_xor(v, 1, 64));
        v = fmaxf(v, __shfl_xor(v, 2, 64));
        v = fmaxf(v, __shfl_xor(v, 4, 64));
        v = fmaxf(v, __shfl_xor(v, 8, 64));
        rm[m][r] = v;
      }
    if (ln == 0) {
#pragma unroll
      for (int m = 0; m < 2; ++m)
#pragma unroll
        for (int r = 0; r < 4; ++r) redm[(m * 16 + g * 4 + r) * 8 + w] = rm[m][r];
    }
    __syncthreads();
#pragma unroll
    for (int m = 0; m < 2; ++m)
#pragma unroll
      for (int r = 0; r < 4; ++r) {
        const float* rp = redm + (m * 16 + g * 4 + r) * 8;
        float v = fmaxf(fmaxf(rp[0], rp[1]), fmaxf(rp[2], rp[3]));
        v = fmaxf(v, fmaxf(fmaxf(rp[4], rp[5]), fmaxf(rp[6], rp[7])));
        rm[m][r] = v;
      }

    // exp and row sum
    float sm[2][4];
#pragma unroll
    for (int m = 0; m < 2; ++m)
#pragma unroll
      for (int r = 0; r < 4; ++r) sm[m][r] = 0.f;
#pragma unroll
    for (int m = 0; m < 2; ++m)
#pragma unroll
      for (int n = 0; n < 8; ++n)
#pragma unroll
        for (int r = 0; r < 4; ++r) {
          const float p = __expf(acc[m][n][r] - rm[m][r]);
          acc[m][n][r] = p;
          sm[m][r] += p;
        }
#pragma unroll
    for (int m = 0; m < 2; ++m)
#pragma unroll
      for (int r = 0; r < 4; ++r) {
        float v = sm[m][r];
        v += __shfl_xor(v, 1, 64);
        v += __shfl_xor(v, 2, 64);
        v += __shfl_xor(v, 4, 64);
        v += __shfl_xor(v, 8, 64);
        sm[m][r] = v;
      }
    if (ln == 0) {
#pragma unroll
      for (int m = 0; m < 2; ++m)
#pragma unroll
        for (int r = 0; r < 4; ++r) reds[(m * 16 + g * 4 + r) * 8 + w] = sm[m][r];
    }
    __syncthreads();
#pragma unroll
    for (int m = 0; m < 2; ++m)
#pragma unroll
      for (int r = 0; r < 4; ++r) {
        const float* rp = reds + (m * 16 + g * 4 + r) * 8;
        const float S = ((rp[0] + rp[1]) + (rp[2] + rp[3])) + ((rp[4] + rp[5]) + (rp[6] + rp[7]));
        const float scale = tp_s[(m * 16 + g * 4 + r) * 16 + e] * __builtin_amdgcn_rcpf(S);
#pragma unroll
        for (int n = 0; n < 8; ++n)
          out_acc[m][n][r] += scale * acc[m][n][r];
      }
  }

  // ---- write out [32][1024] fp32 ----
#pragma unroll
  for (int m = 0; m < 2; ++m)
#pragma unroll
    for (int r = 0; r < 4; ++r) {
      float* op = OUT + (size_t)(b0 + m * 16 + g * 4 + r) * NU + w * 128 + ln;
#pragma unroll
      for (int n = 0; n < 8; ++n) op[n * 16] = out_acc[m][n][r];
    }
}

extern "C" void kernel_launch(void* const* d_in, const int* in_sizes, int n_in,
                              void* d_out, int out_size, void* d_ws, size_t ws_size,
                              hipStream_t stream) {
  const float* X = (const float*)d_in[0];     // [8192,1024] f32
  const float* TP = (const float*)d_in[1];    // [8192,16,1] f32
  const float* W = (const float*)d_in[2];     // [16,1024,1024] f32
  const float* BIAS = (const float*)d_in[3];  // [16,1024] f32
  float* OUT = (float*)d_out;                 // [8192,1024] f32
  f16* WT = (f16*)d_ws;                       // [16,1024,1024] f16 = 33.5 MB

  k_transpose_cast<<<dim3(16, 16, 16), dim3(256), 0, stream>>>(W, WT);
  k_proj<<<dim3(256), dim3(512), 0, stream>>>(X, TP, WT, BIAS, OUT);
}